// Round 15
// baseline (256.773 us; speedup 1.0000x reference)
//
#include <hip/hip_runtime.h>
#include <hip/hip_bf16.h>

#define TSTEPS 60

typedef __attribute__((ext_vector_type(8))) short bf16x8;
typedef __attribute__((ext_vector_type(16))) float f32x16;
typedef __attribute__((ext_vector_type(2))) float f32x2;

// Setup-only scalar conversions.
__device__ __forceinline__ short f2bf(float f) {
    return __builtin_bit_cast(short, __float2bfloat16(f));
}
__device__ __forceinline__ float bf2f(short s) {
    return __builtin_bit_cast(float, (unsigned)(unsigned short)s << 16);
}
// Hot-path pack: two f32 -> u32 of 2 bf16 (round-to-nearest, ties away).
// Merge via v_perm_b32. Do NOT use v_cvt_pk asm (R5 blowup).
__device__ __forceinline__ unsigned pack2_bf16(float a, float b) {
    unsigned ua = __builtin_bit_cast(unsigned, a) + 0x8000u;
    unsigned ub = __builtin_bit_cast(unsigned, b) + 0x8000u;
    return __builtin_amdgcn_perm(ub, ua, 0x07060302u);
}
__device__ __forceinline__ unsigned pack2_bf16_v(f32x2 v) {
    return pack2_bf16(v[0], v[1]);
}

// One wave = 32 samples via 32x32x16 MFMA; chain-minimized recurrence.
//   P_t   = [W1^T|b1] @ [f_t;0;1]          (MFMA, pipelined one step AHEAD, off-chain)
//   h1_t  = relu(P_t + w1d * delta_{t-1})  (packed-f32 VALU inject)
//   h2_t  = [W2^T|b2] @ [h1;1]             (4 independent 2-deep MFMA chains + pk-add merge)
//   delta = relu(h2).W3 + b3               (4-chain packed dot + shfl_xor(32))
// Features are prefetched at distance 2 (ping-pong GA/GB buffers): step t
// issues loads for f(t+2), consumes f(t+1) loaded a full step earlier --
// covers L2 (~200cy) and HBM (~900cy) first-touch latency off the chain.
// Frags: A row=lane&31, k=8*(lane>>5)+j ; D col=lane&31, row=(reg&3)+8*(reg>>2)+4*(lane>>5).
//
// HAZARD (R10 + R13, twice-confirmed): permlane32_swap SELF-reduction is
// broken -- swap(p, p) AND swap(p, forced_copy(p)) both degenerate (absmax
// 0.34375 both times). BANNED. Only use permlane32_swap with two distinct
// VALUES whose two results are both consumed (the relayout below, R9-proven).
// Cross-half self-reduction must use __shfl_xor (proven R3-R14).
__global__ __launch_bounds__(256, 2)
void ffn_mfma32(const float* __restrict__ feat,
                const float* __restrict__ W1, const float* __restrict__ b1,
                const float* __restrict__ W2, const float* __restrict__ b2,
                const float* __restrict__ W3, const float* __restrict__ b3,
                float* __restrict__ out, int N) {
    __shared__ float dlt[4][32 * 61]; // per-wave output staging, stride 61 = conflict-free

    const int lane = threadIdx.x & 63;
    const int wave = threadIdx.x >> 6;
    const int col  = lane & 31;   // sample column
    const int half = lane >> 5;   // k-group half
    const int nbase = blockIdx.x * 128 + wave * 32;
    if (nbase >= N) return;       // wave-uniform

    // ---- loop-invariant fragments ----
    bf16x8 a1[2];
#pragma unroll
    for (int m = 0; m < 2; ++m) {
        bf16x8 v = {0,0,0,0,0,0,0,0};
        if (half == 0) {
            const int row = m*32 + col;
#pragma unroll
            for (int j = 0; j < 4; ++j) v[j] = f2bf(W1[j*64 + row]);
            v[4] = f2bf(b1[row]);
        }
        a1[m] = v;
    }
    bf16x8 a2[2][5];
#pragma unroll
    for (int m = 0; m < 2; ++m) {
        const int row = m*32 + col;
#pragma unroll
        for (int kt = 0; kt < 4; ++kt) {
            bf16x8 v;
#pragma unroll
            for (int j = 0; j < 8; ++j)
                v[j] = f2bf(W2[(16*kt + 8*half + j)*64 + row]);
            a2[m][kt] = v;
        }
        bf16x8 v = {0,0,0,0,0,0,0,0};
        if (half == 0) v[0] = f2bf(b2[row]);
        a2[m][4] = v;
    }
    // W3 and W1-delta-row in D layout, f32x2 pairs (v_pk_fma_f32 formation).
    f32x2 w3f[2][8], w1d[2][8];
#pragma unroll
    for (int m = 0; m < 2; ++m)
#pragma unroll
        for (int r = 0; r < 8; ++r) {
            const int r0 = 2*r, r1 = 2*r + 1;
            const int row0 = m*32 + (r0&3) + 8*(r0>>2) + 4*half;
            const int row1 = m*32 + (r1&3) + 8*(r1>>2) + 4*half;
            w3f[m][r] = (f32x2){ W3[row0], W3[row1] };
            w1d[m][r] = (f32x2){ bf2f(f2bf(W1[3*64 + row0])), bf2f(f2bf(W1[3*64 + row1])) };
        }
    const float b3v = b3[0];

    // Ones B-frag for L2's bias K-tile (half-1 lanes' rows hit zero A coeffs).
    uint4 onesu; onesu.x = 0x3F80u; onesu.y = 0u; onesu.z = 0u; onesu.w = 0u;
    const bf16x8 hb4 = __builtin_bit_cast(bf16x8, onesu);

    f32x16 zc;
#pragma unroll
    for (int r = 0; r < 16; ++r) zc[r] = 0.0f;
    const f32x2 z2 = {0.f, 0.f};

    const float* fp = feat + (size_t)(nbase + col) * (TSTEPS * 3);
    float* dl = dlt[wave];

    // Prologue: P for t=0 from f(0); GA = f(1) (consumed at step 0 for P(1)).
    f32x16 PA0, PA1, PB0, PB1;
    {
        uint4 xu;
        xu.x = pack2_bf16(fp[0], fp[1]);
        xu.y = pack2_bf16(fp[2], 0.f);
        xu.z = 0x3F80u; xu.w = 0u;
        const bf16x8 xb = __builtin_bit_cast(bf16x8, xu);
        PA0 = __builtin_amdgcn_mfma_f32_32x32x16_bf16(a1[0], xb, zc, 0, 0, 0);
        PA1 = __builtin_amdgcn_mfma_f32_32x32x16_bf16(a1[1], xb, zc, 0, 0, 0);
    }
    float ga0 = fp[3], ga1 = fp[4], ga2 = fp[5];   // f(1)
    float gb0 = 0.f, gb1 = 0.f, gb2 = 0.f;         // filled at step 0 with f(2)
    float delta = 0.0f;

    // One step. Pc = current pre-activation; Pn = next step's (built from gf,
    // which holds f(t+1), loaded one full step ago). hf <- f(t+2) loads.
    auto stepfn = [&](int t, const f32x16& Pc0, const f32x16& Pc1,
                      f32x16& Pn0, f32x16& Pn1,
                      float gf0, float gf1, float gf2,
                      float& hf0, float& hf1, float& hf2) {
        // Earliest issue: prefetch f(t+2) (distance-2, fully latency-covered).
        const int t2 = (t + 2 < TSTEPS) ? t + 2 : TSTEPS - 1;
        hf0 = fp[t2*3+0]; hf1 = fp[t2*3+1]; hf2 = fp[t2*3+2];

        // Off-chain: bias MFMAs (invariant operands) = C-init of the 'a' chains.
        f32x16 acc0 = __builtin_amdgcn_mfma_f32_32x32x16_bf16(a2[0][4], hb4, zc, 0, 0, 0);
        f32x16 acc1 = __builtin_amdgcn_mfma_f32_32x32x16_bf16(a2[1][4], hb4, zc, 0, 0, 0);

        // Critical chain: packed-f32 delta injection + relu + perm-pack.
        const f32x2 dv = {delta, delta};
        unsigned pu[2][4], pv[2][4];
#pragma unroll
        for (int m = 0; m < 2; ++m) {
            const f32x16& P = m ? Pc1 : Pc0;
#pragma unroll
            for (int q = 0; q < 4; ++q) {
                f32x2 Plo = { P[4*q+0], P[4*q+1] };
                f32x2 Phi = { P[4*q+2], P[4*q+3] };
                f32x2 rlo = __builtin_elementwise_max(
                    __builtin_elementwise_fma(w1d[m][2*q+0], dv, Plo), z2);
                f32x2 rhi = __builtin_elementwise_max(
                    __builtin_elementwise_fma(w1d[m][2*q+1], dv, Phi), z2);
                pu[m][q] = pack2_bf16_v(rlo);
                pv[m][q] = pack2_bf16_v(rhi);
            }
        }

        // In-register D->B relayout: 2 permlane32_swap per K-tile (distinct
        // values, both results consumed -- the SAFE pattern).
        bf16x8 hbf[4];
#pragma unroll
        for (int kt = 0; kt < 4; ++kt) {
            const int m = kt >> 1, q0 = (kt & 1) * 2;
            auto s0 = __builtin_amdgcn_permlane32_swap(pu[m][q0], pu[m][q0+1], false, false);
            auto s1 = __builtin_amdgcn_permlane32_swap(pv[m][q0], pv[m][q0+1], false, false);
            uint4 w;
            w.x = s0[0]; w.y = s1[0]; w.z = s0[1]; w.w = s1[1];
            hbf[kt] = __builtin_bit_cast(bf16x8, w);
        }

        // L2: 4 independent 2-deep MFMA chains ('a' carries bias C-init).
        __builtin_amdgcn_s_setprio(1);
        f32x16 acc0a = __builtin_amdgcn_mfma_f32_32x32x16_bf16(a2[0][0], hbf[0], acc0, 0, 0, 0);
        f32x16 acc1a = __builtin_amdgcn_mfma_f32_32x32x16_bf16(a2[1][0], hbf[0], acc1, 0, 0, 0);
        f32x16 acc0b = __builtin_amdgcn_mfma_f32_32x32x16_bf16(a2[0][2], hbf[2], zc, 0, 0, 0);
        f32x16 acc1b = __builtin_amdgcn_mfma_f32_32x32x16_bf16(a2[1][2], hbf[2], zc, 0, 0, 0);
        acc0a = __builtin_amdgcn_mfma_f32_32x32x16_bf16(a2[0][1], hbf[1], acc0a, 0, 0, 0);
        acc1a = __builtin_amdgcn_mfma_f32_32x32x16_bf16(a2[1][1], hbf[1], acc1a, 0, 0, 0);
        acc0b = __builtin_amdgcn_mfma_f32_32x32x16_bf16(a2[0][3], hbf[3], acc0b, 0, 0, 0);
        acc1b = __builtin_amdgcn_mfma_f32_32x32x16_bf16(a2[1][3], hbf[3], acc1b, 0, 0, 0);
        __builtin_amdgcn_s_setprio(0);

        // Off-chain: next step's delta-independent L1 from gf (= f(t+1),
        // loaded one full step ago -- no load latency on this path).
        {
            uint4 xu;
            xu.x = pack2_bf16(gf0, gf1);
            xu.y = pack2_bf16(gf2, 0.f);
            xu.z = 0x3F80u; xu.w = 0u;
            const bf16x8 xb = __builtin_bit_cast(bf16x8, xu);
            Pn0 = __builtin_amdgcn_mfma_f32_32x32x16_bf16(a1[0], xb, zc, 0, 0, 0);
            Pn1 = __builtin_amdgcn_mfma_f32_32x32x16_bf16(a1[1], xb, zc, 0, 0, 0);
        }

        // Merge the split chains (packed f32 adds, depth 1).
        const f32x16 accm0 = acc0a + acc0b;
        const f32x16 accm1 = acc1a + acc1b;

        // L3 dot: 4 packed accumulators, depth 4 (R12-proven tree form).
        f32x2 pa = z2, pb = z2, pc = z2, pd = z2;
#pragma unroll
        for (int q = 0; q < 4; ++q) {
            f32x2 a0lo = { accm0[4*q+0], accm0[4*q+1] };
            f32x2 a0hi = { accm0[4*q+2], accm0[4*q+3] };
            f32x2 a1lo = { accm1[4*q+0], accm1[4*q+1] };
            f32x2 a1hi = { accm1[4*q+2], accm1[4*q+3] };
            pa = __builtin_elementwise_fma(__builtin_elementwise_max(a0lo, z2), w3f[0][2*q+0], pa);
            pb = __builtin_elementwise_fma(__builtin_elementwise_max(a0hi, z2), w3f[0][2*q+1], pb);
            pc = __builtin_elementwise_fma(__builtin_elementwise_max(a1lo, z2), w3f[1][2*q+0], pc);
            pd = __builtin_elementwise_fma(__builtin_elementwise_max(a1hi, z2), w3f[1][2*q+1], pd);
        }
        const f32x2 ps = (pa + pb) + (pc + pd);
        float p = ps[0] + ps[1];
        p += __shfl_xor(p, 32, 64);   // cross-half sum (proven; see hazard note)
        delta = p + b3v;

        if (half == 0) dl[col*61 + t] = delta;
    };

    // Ping-pong P and feature buffers: no register copies between steps.
#pragma unroll 1
    for (int t = 0; t < TSTEPS; t += 2) {
        stepfn(t,     PA0, PA1, PB0, PB1, ga0, ga1, ga2, gb0, gb1, gb2);
        stepfn(t + 1, PB0, PB1, PA0, PA1, gb0, gb1, gb2, ga0, ga1, ga2);
    }

    // Coalesced flush: out[nbase*60 + i], i = col*60 + t ; LDS idx = i + i/60.
    float* ob = out + (size_t)nbase * TSTEPS;
#pragma unroll 1
    for (int i = lane; i < 32 * TSTEPS; i += 64) {
        const int cc = i / TSTEPS;
        ob[i] = dl[i + cc];
    }
}

extern "C" void kernel_launch(void* const* d_in, const int* in_sizes, int n_in,
                              void* d_out, int out_size, void* d_ws, size_t ws_size,
                              hipStream_t stream) {
    const float* feat = (const float*)d_in[0];
    const float* W1   = (const float*)d_in[1];
    const float* b1   = (const float*)d_in[2];
    const float* W2   = (const float*)d_in[3];
    const float* b2   = (const float*)d_in[4];
    const float* W3   = (const float*)d_in[5];
    const float* b3   = (const float*)d_in[6];
    float* out = (float*)d_out;

    const int N = in_sizes[0] / (TSTEPS * 3);
    const int block = 256;                  // 4 waves x 32 samples = 128 samples/block
    const int grid = (N + 127) / 128;
    ffn_mfma32<<<grid, block, 0, stream>>>(feat, W1, b1, W2, b2, W3, b3, out, N);
}

// Round 16
// 236.864 us; speedup vs baseline: 1.0841x; 1.0841x over previous
//
#include <hip/hip_runtime.h>
#include <hip/hip_bf16.h>

#define TSTEPS 60

typedef __attribute__((ext_vector_type(8))) short bf16x8;
typedef __attribute__((ext_vector_type(16))) float f32x16;
typedef __attribute__((ext_vector_type(2))) float f32x2;

// Setup-only scalar conversions.
__device__ __forceinline__ short f2bf(float f) {
    return __builtin_bit_cast(short, __float2bfloat16(f));
}
__device__ __forceinline__ float bf2f(short s) {
    return __builtin_bit_cast(float, (unsigned)(unsigned short)s << 16);
}
// Hot-path pack: two f32 -> u32 of 2 bf16 (round-to-nearest, ties away).
// Merge via v_perm_b32. Do NOT use v_cvt_pk asm (R5 blowup).
__device__ __forceinline__ unsigned pack2_bf16(float a, float b) {
    unsigned ua = __builtin_bit_cast(unsigned, a) + 0x8000u;
    unsigned ub = __builtin_bit_cast(unsigned, b) + 0x8000u;
    return __builtin_amdgcn_perm(ub, ua, 0x07060302u);
}
__device__ __forceinline__ unsigned pack2_bf16_v(f32x2 v) {
    return pack2_bf16(v[0], v[1]);
}

// One wave = 32 samples via 32x32x16 MFMA; chain-minimized recurrence.
//   P_t   = [W1^T|b1] @ [f_t;0;1]          (MFMA, pipelined one step AHEAD, off-chain)
//   h1_t  = relu(P_t + w1d * delta_{t-1})  (packed-f32 VALU inject)
//   h2_t  = [W2^T|b2] @ [h1;1]             (4 independent 2-deep MFMA chains + pk-add merge)
//   delta = relu(h2).W3 + b3               (4-chain packed dot + shfl_xor(32))
// Features prefetched at distance 2 (ping-pong GA/GB buffers).
// Frags: A row=lane&31, k=8*(lane>>5)+j ; D col=lane&31, row=(reg&3)+8*(reg>>2)+4*(lane>>5).
//
// R16: per-step s_setprio(1)/(0) around the MFMA cluster REMOVED. At ~2
// resident waves/SIMD the partner wave is the only latency cover; boosting
// our priority 120x/wave starves it exactly when it should issue (regime
// mismatch with T5's 8-phase gains).
//
// HAZARD (R10 + R13, twice-confirmed): permlane32_swap SELF-reduction is
// broken (absmax 0.34375 both times, incl. with a forced distinct copy).
// BANNED. Only the two-distinct-values relayout pattern below (R9-proven).
// Cross-half self-reduction must use __shfl_xor (proven R3-R15).
__global__ __launch_bounds__(256, 2)
void ffn_mfma32(const float* __restrict__ feat,
                const float* __restrict__ W1, const float* __restrict__ b1,
                const float* __restrict__ W2, const float* __restrict__ b2,
                const float* __restrict__ W3, const float* __restrict__ b3,
                float* __restrict__ out, int N) {
    __shared__ float dlt[4][32 * 61]; // per-wave output staging, stride 61 = conflict-free

    const int lane = threadIdx.x & 63;
    const int wave = threadIdx.x >> 6;
    const int col  = lane & 31;   // sample column
    const int half = lane >> 5;   // k-group half
    const int nbase = blockIdx.x * 128 + wave * 32;
    if (nbase >= N) return;       // wave-uniform

    // ---- loop-invariant fragments ----
    bf16x8 a1[2];
#pragma unroll
    for (int m = 0; m < 2; ++m) {
        bf16x8 v = {0,0,0,0,0,0,0,0};
        if (half == 0) {
            const int row = m*32 + col;
#pragma unroll
            for (int j = 0; j < 4; ++j) v[j] = f2bf(W1[j*64 + row]);
            v[4] = f2bf(b1[row]);
        }
        a1[m] = v;
    }
    bf16x8 a2[2][5];
#pragma unroll
    for (int m = 0; m < 2; ++m) {
        const int row = m*32 + col;
#pragma unroll
        for (int kt = 0; kt < 4; ++kt) {
            bf16x8 v;
#pragma unroll
            for (int j = 0; j < 8; ++j)
                v[j] = f2bf(W2[(16*kt + 8*half + j)*64 + row]);
            a2[m][kt] = v;
        }
        bf16x8 v = {0,0,0,0,0,0,0,0};
        if (half == 0) v[0] = f2bf(b2[row]);
        a2[m][4] = v;
    }
    // W3 and W1-delta-row in D layout, f32x2 pairs (v_pk_fma_f32 formation).
    f32x2 w3f[2][8], w1d[2][8];
#pragma unroll
    for (int m = 0; m < 2; ++m)
#pragma unroll
        for (int r = 0; r < 8; ++r) {
            const int r0 = 2*r, r1 = 2*r + 1;
            const int row0 = m*32 + (r0&3) + 8*(r0>>2) + 4*half;
            const int row1 = m*32 + (r1&3) + 8*(r1>>2) + 4*half;
            w3f[m][r] = (f32x2){ W3[row0], W3[row1] };
            w1d[m][r] = (f32x2){ bf2f(f2bf(W1[3*64 + row0])), bf2f(f2bf(W1[3*64 + row1])) };
        }
    const float b3v = b3[0];

    // Ones B-frag for L2's bias K-tile (half-1 lanes' rows hit zero A coeffs).
    uint4 onesu; onesu.x = 0x3F80u; onesu.y = 0u; onesu.z = 0u; onesu.w = 0u;
    const bf16x8 hb4 = __builtin_bit_cast(bf16x8, onesu);

    f32x16 zc;
#pragma unroll
    for (int r = 0; r < 16; ++r) zc[r] = 0.0f;
    const f32x2 z2 = {0.f, 0.f};

    const float* fp = feat + (size_t)(nbase + col) * (TSTEPS * 3);
    float* dl = dlt[wave];

    // Prologue: P for t=0 from f(0); GA = f(1).
    f32x16 PA0, PA1, PB0, PB1;
    {
        uint4 xu;
        xu.x = pack2_bf16(fp[0], fp[1]);
        xu.y = pack2_bf16(fp[2], 0.f);
        xu.z = 0x3F80u; xu.w = 0u;
        const bf16x8 xb = __builtin_bit_cast(bf16x8, xu);
        PA0 = __builtin_amdgcn_mfma_f32_32x32x16_bf16(a1[0], xb, zc, 0, 0, 0);
        PA1 = __builtin_amdgcn_mfma_f32_32x32x16_bf16(a1[1], xb, zc, 0, 0, 0);
    }
    float ga0 = fp[3], ga1 = fp[4], ga2 = fp[5];   // f(1)
    float gb0 = 0.f, gb1 = 0.f, gb2 = 0.f;         // filled at step 0 with f(2)
    float delta = 0.0f;

    auto stepfn = [&](int t, const f32x16& Pc0, const f32x16& Pc1,
                      f32x16& Pn0, f32x16& Pn1,
                      float gf0, float gf1, float gf2,
                      float& hf0, float& hf1, float& hf2) {
        // Prefetch f(t+2) (distance-2, latency-covered).
        const int t2 = (t + 2 < TSTEPS) ? t + 2 : TSTEPS - 1;
        hf0 = fp[t2*3+0]; hf1 = fp[t2*3+1]; hf2 = fp[t2*3+2];

        // Off-chain: bias MFMAs (invariant operands) = C-init of the 'a' chains.
        f32x16 acc0 = __builtin_amdgcn_mfma_f32_32x32x16_bf16(a2[0][4], hb4, zc, 0, 0, 0);
        f32x16 acc1 = __builtin_amdgcn_mfma_f32_32x32x16_bf16(a2[1][4], hb4, zc, 0, 0, 0);

        // Critical chain: packed-f32 delta injection + relu + perm-pack.
        const f32x2 dv = {delta, delta};
        unsigned pu[2][4], pv[2][4];
#pragma unroll
        for (int m = 0; m < 2; ++m) {
            const f32x16& P = m ? Pc1 : Pc0;
#pragma unroll
            for (int q = 0; q < 4; ++q) {
                f32x2 Plo = { P[4*q+0], P[4*q+1] };
                f32x2 Phi = { P[4*q+2], P[4*q+3] };
                f32x2 rlo = __builtin_elementwise_max(
                    __builtin_elementwise_fma(w1d[m][2*q+0], dv, Plo), z2);
                f32x2 rhi = __builtin_elementwise_max(
                    __builtin_elementwise_fma(w1d[m][2*q+1], dv, Phi), z2);
                pu[m][q] = pack2_bf16_v(rlo);
                pv[m][q] = pack2_bf16_v(rhi);
            }
        }

        // In-register D->B relayout: 2 permlane32_swap per K-tile (distinct
        // values, both results consumed -- the SAFE pattern).
        bf16x8 hbf[4];
#pragma unroll
        for (int kt = 0; kt < 4; ++kt) {
            const int m = kt >> 1, q0 = (kt & 1) * 2;
            auto s0 = __builtin_amdgcn_permlane32_swap(pu[m][q0], pu[m][q0+1], false, false);
            auto s1 = __builtin_amdgcn_permlane32_swap(pv[m][q0], pv[m][q0+1], false, false);
            uint4 w;
            w.x = s0[0]; w.y = s1[0]; w.z = s0[1]; w.w = s1[1];
            hbf[kt] = __builtin_bit_cast(bf16x8, w);
        }

        // L2: 4 independent 2-deep MFMA chains ('a' carries bias C-init).
        f32x16 acc0a = __builtin_amdgcn_mfma_f32_32x32x16_bf16(a2[0][0], hbf[0], acc0, 0, 0, 0);
        f32x16 acc1a = __builtin_amdgcn_mfma_f32_32x32x16_bf16(a2[1][0], hbf[0], acc1, 0, 0, 0);
        f32x16 acc0b = __builtin_amdgcn_mfma_f32_32x32x16_bf16(a2[0][2], hbf[2], zc, 0, 0, 0);
        f32x16 acc1b = __builtin_amdgcn_mfma_f32_32x32x16_bf16(a2[1][2], hbf[2], zc, 0, 0, 0);
        acc0a = __builtin_amdgcn_mfma_f32_32x32x16_bf16(a2[0][1], hbf[1], acc0a, 0, 0, 0);
        acc1a = __builtin_amdgcn_mfma_f32_32x32x16_bf16(a2[1][1], hbf[1], acc1a, 0, 0, 0);
        acc0b = __builtin_amdgcn_mfma_f32_32x32x16_bf16(a2[0][3], hbf[3], acc0b, 0, 0, 0);
        acc1b = __builtin_amdgcn_mfma_f32_32x32x16_bf16(a2[1][3], hbf[3], acc1b, 0, 0, 0);

        // Off-chain: next step's delta-independent L1 from gf (= f(t+1)).
        {
            uint4 xu;
            xu.x = pack2_bf16(gf0, gf1);
            xu.y = pack2_bf16(gf2, 0.f);
            xu.z = 0x3F80u; xu.w = 0u;
            const bf16x8 xb = __builtin_bit_cast(bf16x8, xu);
            Pn0 = __builtin_amdgcn_mfma_f32_32x32x16_bf16(a1[0], xb, zc, 0, 0, 0);
            Pn1 = __builtin_amdgcn_mfma_f32_32x32x16_bf16(a1[1], xb, zc, 0, 0, 0);
        }

        // Merge the split chains (packed f32 adds, depth 1).
        const f32x16 accm0 = acc0a + acc0b;
        const f32x16 accm1 = acc1a + acc1b;

        // L3 dot: 4 packed accumulators, depth 4 (R12-proven tree form).
        f32x2 pa = z2, pb = z2, pc = z2, pd = z2;
#pragma unroll
        for (int q = 0; q < 4; ++q) {
            f32x2 a0lo = { accm0[4*q+0], accm0[4*q+1] };
            f32x2 a0hi = { accm0[4*q+2], accm0[4*q+3] };
            f32x2 a1lo = { accm1[4*q+0], accm1[4*q+1] };
            f32x2 a1hi = { accm1[4*q+2], accm1[4*q+3] };
            pa = __builtin_elementwise_fma(__builtin_elementwise_max(a0lo, z2), w3f[0][2*q+0], pa);
            pb = __builtin_elementwise_fma(__builtin_elementwise_max(a0hi, z2), w3f[0][2*q+1], pb);
            pc = __builtin_elementwise_fma(__builtin_elementwise_max(a1lo, z2), w3f[1][2*q+0], pc);
            pd = __builtin_elementwise_fma(__builtin_elementwise_max(a1hi, z2), w3f[1][2*q+1], pd);
        }
        const f32x2 ps = (pa + pb) + (pc + pd);
        float p = ps[0] + ps[1];
        p += __shfl_xor(p, 32, 64);   // cross-half sum (proven; see hazard note)
        delta = p + b3v;

        if (half == 0) dl[col*61 + t] = delta;
    };

    // Ping-pong P and feature buffers: no register copies between steps.
#pragma unroll 1
    for (int t = 0; t < TSTEPS; t += 2) {
        stepfn(t,     PA0, PA1, PB0, PB1, ga0, ga1, ga2, gb0, gb1, gb2);
        stepfn(t + 1, PB0, PB1, PA0, PA1, gb0, gb1, gb2, ga0, ga1, ga2);
    }

    // Coalesced flush: out[nbase*60 + i], i = col*60 + t ; LDS idx = i + i/60.
    float* ob = out + (size_t)nbase * TSTEPS;
#pragma unroll 1
    for (int i = lane; i < 32 * TSTEPS; i += 64) {
        const int cc = i / TSTEPS;
        ob[i] = dl[i + cc];
    }
}

extern "C" void kernel_launch(void* const* d_in, const int* in_sizes, int n_in,
                              void* d_out, int out_size, void* d_ws, size_t ws_size,
                              hipStream_t stream) {
    const float* feat = (const float*)d_in[0];
    const float* W1   = (const float*)d_in[1];
    const float* b1   = (const float*)d_in[2];
    const float* W2   = (const float*)d_in[3];
    const float* b2   = (const float*)d_in[4];
    const float* W3   = (const float*)d_in[5];
    const float* b3   = (const float*)d_in[6];
    float* out = (float*)d_out;

    const int N = in_sizes[0] / (TSTEPS * 3);
    const int block = 256;                  // 4 waves x 32 samples = 128 samples/block
    const int grid = (N + 127) / 128;
    ffn_mfma32<<<grid, block, 0, stream>>>(feat, W1, b1, W2, b2, W3, b3, out, N);
}